// Round 3
// baseline (245.125 us; speedup 1.0000x reference)
//
#include <hip/hip_runtime.h>

#define BOUND 1e-6f
#define HALF_PI 1.57079632679489662f

// DPP helper: masked/out-of-range lanes receive `oldv` (we pass 1.0f, the
// multiplicative identity). ctrl/row_mask must be literal constants.
#define UPD_DPP(oldv, srcv, ctrl, rmask)                                        \
  __int_as_float(__builtin_amdgcn_update_dpp(                                   \
      __float_as_int(oldv), __float_as_int(srcv), (ctrl), (rmask), 0xF, false))

// Inclusive multiplicative scan across 64 lanes, pure VALU (validated in R2):
// row_shr:1/2/4/8 within 16-lane rows, then row_bcast15 (rows 1,3) and
// row_bcast31 (rows 2,3). Invalid-source lanes multiply by 1.0.
__device__ __forceinline__ float wave_incl_prod(float x) {
    x *= UPD_DPP(1.0f, x, 0x111, 0xF);  // row_shr:1
    x *= UPD_DPP(1.0f, x, 0x112, 0xF);  // row_shr:2
    x *= UPD_DPP(1.0f, x, 0x114, 0xF);  // row_shr:4
    x *= UPD_DPP(1.0f, x, 0x118, 0xF);  // row_shr:8
    x *= UPD_DPP(1.0f, x, 0x142, 0xA);  // row_bcast:15 -> rows 1,3
    x *= UPD_DPP(1.0f, x, 0x143, 0xC);  // row_bcast:31 -> rows 2,3
    return x;
}

// One wave per row (grid-stride). Lane l owns columns 4l..4l+3 (float4 load).
// Software-pipelined: next row's x is loaded BEFORE computing the current row,
// so every wave keeps 1 KB of reads in flight under the ~240-cycle compute.
// out[j]   = radius * prod_{i<j}(sin(a_i)+B) * (cos(a_j)+B),  j < 256
// out[256] = radius * prod_{i<256}(sin(a_i)+B)
__global__ __launch_bounds__(256) void spherize_kernel(
    const float* __restrict__ x,
    const float* __restrict__ p_phiL,
    const float* __restrict__ p_radius,
    const float* __restrict__ p_scaling,
    float* __restrict__ out,
    int n_rows)
{
    const float phi_L   = p_phiL[0];
    const float radius  = p_radius[0];
    const float scaling = p_scaling[0];
    const float amp     = HALF_PI - phi_L;

    const int lane            = threadIdx.x & 63;
    const int wave_in_block   = threadIdx.x >> 6;
    const int waves_per_block = blockDim.x >> 6;
    const int total_waves     = gridDim.x * waves_per_block;

    int row = blockIdx.x * waves_per_block + wave_in_block;
    if (row >= n_rows) return;

    float4 xv = *reinterpret_cast<const float4*>(x + (size_t)row * 256 + lane * 4);

    for (;;) {
        // ---- prefetch next row (completes under this row's compute) ----
        const int nrow = row + total_waves;
        float4 xn = make_float4(0.f, 0.f, 0.f, 0.f);
        if (nrow < n_rows)
            xn = *reinterpret_cast<const float4*>(x + (size_t)nrow * 256 + lane * 4);

        // ---- elementwise angles (validated math from R1/R2) ----
        const float* xp = &xv.x;
        float s[4], c[4];
        #pragma unroll
        for (int k = 0; k < 4; ++k) {
            float e  = __expf(-scaling * xp[k]);
            float sg = __builtin_amdgcn_rcpf(1.0f + e);
            float a  = fmaf(amp, sg, phi_L);   // a in [phi_L, pi/2)
            s[k] = __sinf(a) + BOUND;
            c[k] = __cosf(a) + BOUND;
        }

        // intra-lane prefix products, then ONE wave scan of lane totals
        float q1 = s[0];
        float q2 = q1 * s[1];
        float q3 = q2 * s[2];
        float t  = q3 * s[3];
        float scan = wave_incl_prod(t);          // inclusive over lanes
        float excl = __shfl_up(scan, 1, 64);     // product of lanes < me
        float base = radius * ((lane == 0) ? 1.0f : excl);

        float* orow = out + (size_t)row * 257 + lane * 4;
        orow[0] = base * c[0];
        orow[1] = base * q1 * c[1];
        orow[2] = base * q2 * c[2];
        orow[3] = base * q3 * c[3];
        if (lane == 63)
            orow[4] = radius * scan;             // col 256: full product

        if (nrow >= n_rows) break;
        xv  = xn;
        row = nrow;
    }
}

extern "C" void kernel_launch(void* const* d_in, const int* in_sizes, int n_in,
                              void* d_out, int out_size, void* d_ws, size_t ws_size,
                              hipStream_t stream) {
    // inputs: 0=x [N,256], 1=W_theta, 2=W_phi, 3=b_phi, 4=phi_L, 5=radius, 6=scaling
    const float* x         = (const float*)d_in[0];
    const float* p_phiL    = (const float*)d_in[4];
    const float* p_radius  = (const float*)d_in[5];
    const float* p_scaling = (const float*)d_in[6];
    float* out = (float*)d_out;

    const int n_rows = in_sizes[0] / 256;
    const int waves_per_block = 256 / 64;
    int blocks = (n_rows + waves_per_block - 1) / waves_per_block;
    if (blocks > 4096) blocks = 4096;   // grid-stride; 32 rows per wave

    spherize_kernel<<<blocks, 256, 0, stream>>>(x, p_phiL, p_radius, p_scaling,
                                                out, n_rows);
}